// Round 16
// baseline (234.538 us; speedup 1.0000x reference)
//
#include <hip/hip_runtime.h>
#include <hip/hip_bf16.h>

#define DD 256
#define SCALAR 30.0f
#define K2 43.28085122666891f     // 30 * log2(e)
#define LN2 0.6931471805599453f
#define NT 8                      // 32-col fp32 tiles per block; 4688 = 586*8

typedef __attribute__((ext_vector_type(8))) short bf16x8;
typedef __attribute__((ext_vector_type(4))) float f32x4;
typedef f32x4 f32x4u __attribute__((aligned(4)));   // 4B-aligned vector loads

__device__ __forceinline__ float fexp2(float x) {
#if __has_builtin(__builtin_amdgcn_exp2f)
    return __builtin_amdgcn_exp2f(x);
#else
    return exp2f(x);
#endif
}

__device__ __forceinline__ unsigned short f2b(float f) {
    __hip_bfloat16 h = __float2bfloat16(f);
    return __builtin_bit_cast(unsigned short, h);
}

__device__ __forceinline__ bf16x8 cvt8(f32x4 a, f32x4 b) {
    bf16x8 r;
    r[0] = (short)f2b(a[0]); r[1] = (short)f2b(a[1]);
    r[2] = (short)f2b(a[2]); r[3] = (short)f2b(a[3]);
    r[4] = (short)f2b(b[0]); r[5] = (short)f2b(b[1]);
    r[6] = (short)f2b(b[2]); r[7] = (short)f2b(b[3]);
    return r;
}

// async global->LDS, 16B per lane; LDS dest = wave-uniform base + lane*16
__device__ __forceinline__ void gload16(const void* g, void* l) {
    __builtin_amdgcn_global_load_lds((const __attribute__((address_space(1))) void*)g,
                                     (__attribute__((address_space(3))) void*)l, 16, 0, 0);
}

// K0: x = l2norm(inputs); fp32 + bf16 copies; zero loss accumulator.
__global__ void prep_kernel(const float* __restrict__ in, float* __restrict__ xf,
                            unsigned short* __restrict__ xb, float* __restrict__ out_loss) {
    int row = blockIdx.x, tid = threadIdx.x;
    __shared__ float red[256];
    float v = in[(size_t)row * DD + tid];
    red[tid] = v * v;
    __syncthreads();
    for (int h = 128; h > 0; h >>= 1) {
        if (tid < h) red[tid] += red[tid + h];
        __syncthreads();
    }
    float nrm = fmaxf(sqrtf(red[0]), 1e-12f);
    float xn = v / nrm;
    xf[(size_t)row * DD + tid] = xn;
    xb[(size_t)row * DD + tid] = f2b(xn);
    if (row == 0 && tid == 0) out_loss[0] = 0.f;
}

// K1: single-pass GEMM + lse partials + fused shifted out-copy. lut/cq read ONCE.
// grid (4 rb, 586 bx), 4 waves/block. Per block: NT=8 fp32 tiles of 32 cols staged
// via global_load_lds (XOR-swizzled SOURCE, linear LDS dest — rule #21); bf16
// conversion in-register per fragment; out-copy = direct global misaligned-16B
// read (L2-hot: same lines the DMA pulled) -> aligned nt store. Counted vmcnt
// discipline for the mixed in-order stream: body issues [cl 2][D 8][cs 2];
// top-waits 8/12/14/..,6; mid vmcnt(8) before stores keeps prefetch in flight.
__global__ __launch_bounds__(256, 2) void gemm_fused_kernel(
    const unsigned short* __restrict__ xb, const float* __restrict__ lut,
    const float* __restrict__ cq, float* __restrict__ dout,
    float* __restrict__ pm, float* __restrict__ ps,
    int N, long PD, long TOT, int GB) {
    __shared__ char Bs[2][32768];
    int tid = threadIdx.x;
    int w = tid >> 6, lane = tid & 63;
    int l15 = lane & 15, lg = lane >> 4;
    int rb = blockIdx.x, bx = blockIdx.y;
    int row0 = rb * 256 + w * 64;
    long MMAX = TOT >> 2;

    // prologue patch (oldest vmem ops; +2 ops for this one block is wait-safe)
    if (rb == 3 && bx == GB - 1 && tid == 0)
        dout[TOT] = cq[TOT - 1 - PD];

    // A -> registers (oldest counted stream): 4 rf x 8 kc x 16B = 128 VGPR
    bf16x8 areg[4][8];
    const char* ab = (const char*)xb + ((size_t)(row0 + l15) * 256 + lg * 8) * 2;
    #pragma unroll
    for (int rf = 0; rf < 4; ++rf)
        #pragma unroll
        for (int kc = 0; kc < 8; ++kc)
            areg[rf][kc] = *(const bf16x8*)(ab + rf * (16 * 512) + kc * 64);

    // fp32 tile DMA: tile g covers floats [g*8192, +8192); source pre-swizzled
    auto stage = [&](int t, int b) {
        long sbase = (long)(bx * NT + t) * 8192;   // PD % 8192 == 0: no straddle
        const float* sbp = (sbase < PD) ? (lut + sbase) : (cq + (sbase - PD));
        #pragma unroll
        for (int r = 0; r < 8; ++r) {
            int s = r * 256 + w * 64 + lane;               // 16B slot index
            long off = 4L * (long)(s ^ ((s >> 6) & 7));    // swizzled source floats
            if (sbase + off >= TOT) off = 0;               // phantom clamp (4-aligned)
            gload16(sbp + off, &Bs[b][(size_t)(r * 256 + w * 64) * 16]);
        }
    };

    stage(0, 0);   // D0
    stage(1, 1);   // D1

    float rm[4], rs[4];
    #pragma unroll
    for (int rf = 0; rf < 4; ++rf) { rm[rf] = -1e30f; rs[rf] = 0.f; }

    #pragma unroll 1
    for (int t = 0; t < NT; ++t) {
        // top wait: tile t resident (in-order counted; see table in header comment)
        if (t == 0)           asm volatile("s_waitcnt vmcnt(8)" ::: "memory");
        else if (t == 1)      asm volatile("s_waitcnt vmcnt(12)" ::: "memory");
        else if (t < NT - 1)  asm volatile("s_waitcnt vmcnt(14)" ::: "memory");
        else                  asm volatile("s_waitcnt vmcnt(6)" ::: "memory");
        __builtin_amdgcn_s_barrier();
        int b = t & 1;
        const char* bufc = &Bs[b][0];

        // ---- copy loads (cl, 2 ops): this block's quarter of tile t's chunks ----
        long mbase = (long)bx * 16384 + (long)t * 2048 + rb * 512;
        f32x4 cv[2];
        bool cok[2], cmz[2], cbd[2];
        float cex[2];
        #pragma unroll
        for (int k = 0; k < 2; ++k) {
            long m = mbase + k * 256 + tid;
            cok[k] = (m < MMAX);
            cmz[k] = false; cbd[k] = false; cex[k] = 0.f;
            if (cok[k]) {
                long sd = 4 * m - 1;
                cmz[k] = (m == 0);
                cbd[k] = (sd == PD - 1);
                const float* ap;
                if (cmz[k])      ap = lut;                 // aligned lut[0..3]
                else if (cbd[k]) ap = cq;                  // aligned cq[0..3]
                else             ap = (sd < PD) ? (lut + sd) : (cq + (sd - PD));
                cv[k] = *(const f32x4u*)ap;
                if (cbd[k]) cex[k] = lut[PD - 1];          // extra op: wait-safe
            }
        }

        // ---- MFMA: ds_read fp32 fragments, cvt to bf16 in-register ----
        f32x4 acc[2][4];   // [cf][rf]
        #pragma unroll
        for (int cf = 0; cf < 2; ++cf)
            #pragma unroll
            for (int rf = 0; rf < 4; ++rf) acc[cf][rf] = (f32x4){0.f, 0.f, 0.f, 0.f};

        #pragma unroll
        for (int k0 = 0; k0 < 8; ++k0) {
            bf16x8 bb[2];
            #pragma unroll
            for (int cf = 0; cf < 2; ++cf) {
                int col = cf * 16 + l15;
                int c7 = col & 7;
                int sl = k0 * 8 + lg * 2;
                f32x4 fa = *(const f32x4*)(bufc + (size_t)((col * 64 + (sl ^ c7)) << 4));
                f32x4 fb = *(const f32x4*)(bufc + (size_t)((col * 64 + ((sl + 1) ^ c7)) << 4));
                bb[cf] = cvt8(fa, fb);
            }
            #pragma unroll
            for (int rf = 0; rf < 4; ++rf)
                #pragma unroll
                for (int cf = 0; cf < 2; ++cf)
                    acc[cf][rf] = __builtin_amdgcn_mfma_f32_16x16x32_bf16(bb[cf], areg[rf][k0], acc[cf][rf], 0, 0, 0);
        }

        asm volatile("s_waitcnt lgkmcnt(0)" ::: "memory");
        __builtin_amdgcn_s_barrier();

        // ---- prefetch DMA tile t+2 into the freed buffer (D, 8 ops) ----
        if (t + 2 < NT) stage(t + 2, b);

        // ---- copy stores (cs, 2 ops); keep the DMA in flight ----
        if (t < NT - 2) asm volatile("s_waitcnt vmcnt(8)" ::: "memory");
        else            asm volatile("s_waitcnt vmcnt(0)" ::: "memory");
        #pragma unroll
        for (int k = 0; k < 2; ++k) {
            if (cok[k]) {
                long m = mbase + k * 256 + tid;
                f32x4 v = cv[k], o;
                if (cmz[k])      o = (f32x4){0.f,    v[0], v[1], v[2]};   // dout[0]=loss(0)
                else if (cbd[k]) o = (f32x4){cex[k], v[0], v[1], v[2]};   // lut/cq boundary
                else             o = v;
                __builtin_nontemporal_store(o, (f32x4*)(dout + 4 * m));
            }
        }

        // ---- fold (register-only) ----
        bool lastT = (bx == GB - 1) && (t == NT - 1);   // cols 150000..150015 phantom
        #pragma unroll
        for (int rf = 0; rf < 4; ++rf) {
            float lmraw = acc[0][rf][0];
            #pragma unroll
            for (int r = 1; r < 4; ++r) lmraw = fmaxf(lmraw, acc[0][rf][r]);
            if (!lastT) {
                #pragma unroll
                for (int r = 0; r < 4; ++r) lmraw = fmaxf(lmraw, acc[1][rf][r]);
            }
            float lm = fmaxf(rm[rf], K2 * lmraw);
            float ls = rs[rf] * fexp2(rm[rf] - lm);
            #pragma unroll
            for (int r = 0; r < 4; ++r) ls += fexp2(fmaf(K2, acc[0][rf][r], -lm));
            if (!lastT) {
                #pragma unroll
                for (int r = 0; r < 4; ++r) ls += fexp2(fmaf(K2, acc[1][rf][r], -lm));
            }
            rm[rf] = lm; rs[rf] = ls;
        }
    }

    // cross-lane-group merge (copies at lanes l15+16k)
    #pragma unroll
    for (int rf = 0; rf < 4; ++rf) {
        float m = rm[rf], s = rs[rf];
        float m1 = __shfl_xor(m, 16), s1 = __shfl_xor(s, 16);
        float M = fmaxf(m, m1);
        s = s * fexp2(m - M) + s1 * fexp2(m1 - M);
        m = M;
        m1 = __shfl_xor(m, 32); s1 = __shfl_xor(s, 32);
        M = fmaxf(m, m1);
        s = s * fexp2(m - M) + s1 * fexp2(m1 - M);
        if (lg == 0) {
            size_t idx = (size_t)bx * N + row0 + rf * 16 + l15;
            pm[idx] = M;
            ps[idx] = s;
        }
    }
}

// K2: per-row combine of GB partials -> lse (log2 domain); exact label logit; loss.
__global__ void finalize_kernel(const float* __restrict__ pm, const float* __restrict__ ps,
                                const float* __restrict__ xf, const float* __restrict__ lut,
                                const int* __restrict__ label, float* __restrict__ out_loss,
                                int CB, int N, int P) {
    int row = blockIdx.x, tid = threadIdx.x;
    int y = label[row];
    if (y >= P) return;   // unlabeled -> ce contribution 0
    __shared__ float sm[256], ss[256], sd[256];
    __shared__ int snz[256];
    float m = -1e30f, s = 0.f;
    for (int cb = tid; cb < CB; cb += 256) {
        float bm = pm[(size_t)cb * N + row];
        float bs = ps[(size_t)cb * N + row];
        float M = fmaxf(m, bm);
        s = s * fexp2(m - M) + bs * fexp2(bm - M);
        m = M;
    }
    float lv = lut[(size_t)y * DD + tid];
    sm[tid] = m; ss[tid] = s;
    sd[tid] = xf[(size_t)row * DD + tid] * lv;
    snz[tid] = (lv != 0.f) ? 1 : 0;
    __syncthreads();
    for (int h = 128; h > 0; h >>= 1) {
        if (tid < h) {
            float m2 = sm[tid + h], s2 = ss[tid + h];
            float M = fmaxf(sm[tid], m2);
            ss[tid] = ss[tid] * fexp2(sm[tid] - M) + s2 * fexp2(m2 - M);
            sm[tid] = M;
            sd[tid] += sd[tid + h];
            snz[tid] |= snz[tid + h];
        }
        __syncthreads();
    }
    if (tid == 0) {
        bool bad = (snz[0] == 0);          // own prototype empty -> logit forced to +30
        float lse = LN2 * (sm[0] + log2f(ss[0]));
        float llab = bad ? SCALAR : SCALAR * sd[0];
        atomicAdd(out_loss, (lse - llab) / (float)N);
    }
}

// K3: memory-bank update. One wave per sample; wave-parallel ballot scans.
__global__ __launch_bounds__(64) void update_kernel(
    const float* __restrict__ xf, const int* __restrict__ label,
    const float* __restrict__ ious, const float* __restrict__ lut,
    const int* __restrict__ header, float* __restrict__ out_lut,
    float* __restrict__ out_cq, int N, int P, int Q) {
    extern __shared__ char smem[];
    int* slab = (int*)smem;
    float* siou = (float*)(smem + sizeof(int) * (size_t)N);
    int i = blockIdx.x, lane = threadIdx.x;
    for (int j = lane; j < N; j += 64) { slab[j] = label[j]; siou[j] = ious[j]; }
    __syncthreads();

    float s = 0.f;
    for (int j = lane; j < N; j += 64) s += siou[j];
    #pragma unroll
    for (int off = 32; off > 0; off >>= 1) s += __shfl_xor(s, off);
    if (s >= 0.2f * (float)N) return;   // ious.mean() >= 0.2 -> no update

    int y = slab[i];
    if (y < P) {
        unsigned long long m[16];
        #pragma unroll
        for (int c = 0; c < 16; ++c) {
            int j = c * 64 + lane;
            m[c] = __ballot(j < N && slab[j] == y);
        }
        int first = -1;
        #pragma unroll
        for (int c = 0; c < 16; ++c)
            if (first < 0 && m[c] != 0ull) first = c * 64 + (int)__builtin_ctzll(m[c]);
        if (first != i) return;   // only the first occurrence drives this label

        float4 r = *(const float4*)(lut + (size_t)y * DD + lane * 4);
        for (int pass = 0; pass < 2; ++pass) {
            #pragma unroll
            for (int c = 0; c < 16; ++c) {
                unsigned long long mm = m[c];
                while (mm) {
                    int j = c * 64 + (int)__builtin_ctzll(mm);
                    mm &= mm - 1;
                    float b = (pass == 0) ? 0.5f : siou[j];
                    float a = 1.f - b;
                    float4 xj = *(const float4*)(xf + (size_t)j * DD + lane * 4);
                    r.x = a * r.x + b * xj.x;
                    r.y = a * r.y + b * xj.y;
                    r.z = a * r.z + b * xj.z;
                    r.w = a * r.w + b * xj.w;
                    float ss2 = r.x * r.x + r.y * r.y + r.z * r.z + r.w * r.w;
                    #pragma unroll
                    for (int off = 32; off > 0; off >>= 1) ss2 += __shfl_xor(ss2, off);
                    float inv = 1.f / fmaxf(sqrtf(ss2), 1e-12f);
                    r.x *= inv; r.y *= inv; r.z *= inv; r.w *= inv;
                }
            }
        }
        float* dst = out_lut + (size_t)y * DD + lane * 4;
        dst[0] = r.x; dst[1] = r.y; dst[2] = r.z; dst[3] = r.w;
    } else {
        int rank = 0, U = 0;
        #pragma unroll
        for (int c = 0; c < 16; ++c) {
            int j = c * 64 + lane;
            unsigned long long u = __ballot(j < N && slab[j] >= P);
            U += __popcll(u);
            int base = c * 64;
            if (base + 64 <= i)      rank += __popcll(u);
            else if (base < i)       rank += __popcll(u & ((1ull << (i - base)) - 1ull));
        }
        int h0 = header[0];
        float4 xi = *(const float4*)(xf + (size_t)i * DD + lane * 4);
        long long p1 = ((long long)h0 + rank) % Q;
        long long p2 = ((long long)h0 + U + rank) % Q;
        float* d1 = out_cq + (size_t)p1 * DD + lane * 4;
        float* d2 = out_cq + (size_t)p2 * DD + lane * 4;
        d1[0] = xi.x; d1[1] = xi.y; d1[2] = xi.z; d1[3] = xi.w;
        d2[0] = xi.x; d2[1] = xi.y; d2[2] = xi.z; d2[3] = xi.w;
    }
}

extern "C" void kernel_launch(void* const* d_in, const int* in_sizes, int n_in,
                              void* d_out, int out_size, void* d_ws, size_t ws_size,
                              hipStream_t stream) {
    const float* inputs = (const float*)d_in[0];
    const int* label    = (const int*)d_in[1];
    const float* ious   = (const float*)d_in[2];
    const float* lut    = (const float*)d_in[3];
    const float* cq     = (const float*)d_in[4];
    const int* header   = (const int*)d_in[5];
    float* out = (float*)d_out;

    int N = in_sizes[0] / DD;            // 1024
    int P = in_sizes[3] / DD;            // 100000
    int Q = in_sizes[4] / DD;            // 50000
    int C = P + Q;                       // 150000
    int SUB = (C + 31) / 32;             // 32-col tiles = 4688
    int GB = (SUB + NT - 1) / NT;        // 586 (4688 = 586*8 exact)
    long PD = (long)P * DD;
    long TOT = (long)C * DD;

    // workspace: xf(1MB) | xb(0.5MB) | pm(2.4MB) | ps(2.4MB)
    char* ws = (char*)d_ws;
    float* xf = (float*)ws;
    unsigned short* xb = (unsigned short*)(ws + (size_t)N * DD * 4);
    float* pm = (float*)(ws + (size_t)N * DD * 6);
    float* ps = pm + (size_t)GB * N;

    float* out_loss = out;
    float* out_lut  = out + 1;
    float* out_cq   = out + 1 + (size_t)P * DD;

    hipLaunchKernelGGL(prep_kernel, dim3(N), dim3(256), 0, stream, inputs, xf, xb, out_loss);
    hipLaunchKernelGGL(gemm_fused_kernel, dim3(4, GB), dim3(256), 0, stream,
                       xb, lut, cq, out, pm, ps, N, PD, TOT, GB);
    hipLaunchKernelGGL(finalize_kernel, dim3(N), dim3(256), 0, stream,
                       pm, ps, xf, lut, label, out_loss, GB, N, P);
    hipLaunchKernelGGL(update_kernel, dim3(N), dim3(64), (size_t)N * 8, stream,
                       xf, label, ious, lut, header, out_lut, out_cq, N, P, Q);
}

// Round 17
// 197.381 us; speedup vs baseline: 1.1882x; 1.1882x over previous
//
#include <hip/hip_runtime.h>
#include <hip/hip_bf16.h>

#define DD 256
#define SCALAR 30.0f
#define K2 43.28085122666891f     // 30 * log2(e)
#define LN2 0.6931471805599453f
#define NT 8                      // column-tiles (64 cols) per gemm block; 2344 = 293*8

typedef __attribute__((ext_vector_type(8))) short bf16x8;
typedef __attribute__((ext_vector_type(4))) float f32x4;

__device__ __forceinline__ float fexp2(float x) {
#if __has_builtin(__builtin_amdgcn_exp2f)
    return __builtin_amdgcn_exp2f(x);
#else
    return exp2f(x);
#endif
}

// RNE float->bf16 (no-NaN inputs)
__device__ __forceinline__ unsigned short f2b(float f) {
    unsigned int u = __builtin_bit_cast(unsigned int, f);
    u += 0x7FFFu + ((u >> 16) & 1u);
    return (unsigned short)(u >> 16);
}

// async global->LDS, 16B per lane; LDS dest is wave-uniform base + lane*16
__device__ __forceinline__ void gload16(const void* g, void* l) {
    __builtin_amdgcn_global_load_lds((const __attribute__((address_space(1))) void*)g,
                                     (__attribute__((address_space(3))) void*)l, 16, 0, 0);
}

// K1: blocks [0,N): prep (x=l2norm, xf/xb, zero loss).
//     blocks [N, N+TILES): ONE BT TILE PER BLOCK —
//       (a) read 64 cols fp32 (64KB contiguous span),
//       (b) convert+swizzle into a 32KB LDS image,
//       (c) blast the image to bt LINEARLY (8KB/wave, coalesced — R13's scattered
//           512B bt writes were the K1 rate-limiter at 3.0 TB/s),
//       (d) out-copy the same 64KB span (L2-hot re-read) with nt stores.
// bt tile layout (R13-proven): col c row of 512B; bf16(c,k) at byte
//   c*512 + ((k>>3)^(c&7))*16 + (k&7)*2.
__global__ __launch_bounds__(256) void prep_bt_copy_kernel(
    const float* __restrict__ in, float* __restrict__ xf, unsigned short* __restrict__ xb,
    const float* __restrict__ lut, const float* __restrict__ cq,
    float* __restrict__ out, unsigned short* __restrict__ bt,
    long PD, long TOT, int C, int TILES, int N) {
    __shared__ char sbt[32768];
    int tid = threadIdx.x;
    if ((int)blockIdx.x < N) {
        __shared__ float red[256];
        int row = blockIdx.x;
        float v = in[(size_t)row * DD + tid];
        red[tid] = v * v;
        __syncthreads();
        for (int h = 128; h > 0; h >>= 1) {
            if (tid < h) red[tid] += red[tid + h];
            __syncthreads();
        }
        float nrm = fmaxf(sqrtf(red[0]), 1e-12f);
        float xn = v / nrm;
        xf[(size_t)row * DD + tid] = xn;
        xb[(size_t)row * DD + tid] = f2b(xn);
        if (row == 0 && tid == 0) out[0] = 0.f;
        return;
    }
    int t = blockIdx.x - N;                 // tile id
    int w = tid >> 6, lane = tid & 63;

    // (a)+(b): wave w covers cols {it*4 + w}; lane covers k = lane*4..+3
    #pragma unroll
    for (int it = 0; it < 16; ++it) {
        int c = it * 4 + w;
        int gc = t * 64 + c;
        float4 v = make_float4(0.f, 0.f, 0.f, 0.f);
        if (gc < C) {
            long s = (long)gc * 256 + lane * 4;
            v = (s < PD) ? *(const float4*)(lut + s) : *(const float4*)(cq + (s - PD));
        }
        short4 b;
        b.x = f2b(v.x); b.y = f2b(v.y); b.z = f2b(v.z); b.w = f2b(v.w);
        long toff = (long)c * 512 + (long)((((lane >> 1) ^ (c & 7)) << 4) + (lane & 1) * 8);
        *(short4*)(sbt + toff) = b;
    }
    __syncthreads();

    // (c): linear 32KB blast, 16B per thread per round
    {
        char* dstt = (char*)bt + (size_t)t * 32768;
        #pragma unroll
        for (int i = 0; i < 8; ++i) {
            int off = (i * 256 + tid) * 16;
            *(f32x4*)(dstt + off) = *(const f32x4*)(sbt + off);
        }
    }

    // (d): out-copy span, chunks m in [t*4096, t*4096+4096), dout[4m..] <- flat[4m-1..]
    long m0 = (long)t * 4096;
    long MMAX = TOT >> 2;
    #pragma unroll
    for (int i = 0; i < 16; ++i) {
        long m = m0 + i * 256 + tid;
        float4 v = make_float4(0.f, 0.f, 0.f, 0.f);
        bool ok = (m >= 1 && m < MMAX);
        if (ok) {
            long s = 4 * m;
            v = (s < PD) ? *(const float4*)(lut + s) : *(const float4*)(cq + (s - PD));
        }
        float pw = __shfl_up(v.w, 1);
        if (lane == 0 && ok) {
            long f = 4 * m - 1;
            pw = (f < PD) ? lut[f] : cq[f - PD];
        }
        if (ok) {
            f32x4 o = (f32x4){pw, v.x, v.y, v.z};
            __builtin_nontemporal_store(o, (f32x4*)(out + 4 * m));
        }
    }
    if (t == 0 && tid == 0) {
        out[1] = lut[0]; out[2] = lut[1]; out[3] = lut[2];
    }
    if (t == TILES - 1 && tid == 0)
        out[TOT] = cq[TOT - 1 - PD];
}

// K2: GEMM + per-row (max,sumexp), log2 domain. R13-proven verbatim:
// 4-wave blocks, 64 rows/wave, A in regs (128 VGPR), bt bf16 LDS double-buffer
// via global_load_lds, counted vmcnt(8), fold under the DMA flight.
__global__ __launch_bounds__(256, 2) void gemm_lse_kernel(
    const unsigned short* __restrict__ xb, const unsigned short* __restrict__ bt,
    float* __restrict__ pm, float* __restrict__ ps, int N) {
    __shared__ char Bs[2][32768];
    int tid = threadIdx.x;
    int w = tid >> 6, lane = tid & 63;
    int l15 = lane & 15, lg = lane >> 4;
    int bx = blockIdx.x, rb = blockIdx.y;
    int row0 = rb * 256 + w * 64;
    int xr = l15 & 7;

    const char* gt = (const char*)bt + (size_t)bx * NT * 32768;

    // A -> registers FIRST (oldest in vmcnt order): 4 rf x 8 kc x 16B
    bf16x8 areg[4][8];
    const char* ab = (const char*)xb + ((size_t)(row0 + l15) * 256 + lg * 8) * 2;
    #pragma unroll
    for (int rf = 0; rf < 4; ++rf)
        #pragma unroll
        for (int kc = 0; kc < 8; ++kc)
            areg[rf][kc] = *(const bf16x8*)(ab + rf * (16 * 512) + kc * 64);

    // then DMA tiles 0 and 1 (newest 16 vmem ops; 8KB per wave per tile)
    {
        const char* src = gt + w * 8192 + lane * 16;
        #pragma unroll
        for (int i = 0; i < 8; ++i)
            gload16(src + i * 1024, &Bs[0][w * 8192 + i * 1024]);
        #pragma unroll
        for (int i = 0; i < 8; ++i)
            gload16(src + 32768 + i * 1024, &Bs[1][w * 8192 + i * 1024]);
    }

    float rm[4], rs[4];
    #pragma unroll
    for (int rf = 0; rf < 4; ++rf) { rm[rf] = -1e30f; rs[rf] = 0.f; }

    #pragma unroll 1
    for (int st = 0; st < NT; ++st) {
        if (st < NT - 1) asm volatile("s_waitcnt vmcnt(8)" ::: "memory");
        else             asm volatile("s_waitcnt vmcnt(0)" ::: "memory");
        __builtin_amdgcn_s_barrier();

        const char* bufc = &Bs[st & 1][0];
        f32x4 acc[4][4];   // [cf][rf]
        #pragma unroll
        for (int cf = 0; cf < 4; ++cf)
            #pragma unroll
            for (int rf = 0; rf < 4; ++rf) acc[cf][rf] = (f32x4){0.f, 0.f, 0.f, 0.f};

        #pragma unroll
        for (int k0 = 0; k0 < 8; ++k0) {
            int sl = (((k0 * 4 + lg) ^ xr) << 4);
            bf16x8 b[4];
            #pragma unroll
            for (int cf = 0; cf < 4; ++cf)
                b[cf] = *(const bf16x8*)(bufc + (cf * 16 + l15) * 512 + sl);
            #pragma unroll
            for (int rf = 0; rf < 4; ++rf)
                #pragma unroll
                for (int cf = 0; cf < 4; ++cf)
                    acc[cf][rf] = __builtin_amdgcn_mfma_f32_16x16x32_bf16(b[cf], areg[rf][k0], acc[cf][rf], 0, 0, 0);
        }

        __builtin_amdgcn_s_barrier();
        if (st + 2 < NT) {
            const char* src = gt + (st + 2) * 32768 + w * 8192 + lane * 16;
            char* dst = &Bs[st & 1][w * 8192];
            #pragma unroll
            for (int i = 0; i < 8; ++i)
                gload16(src + i * 1024, dst + i * 1024);
        }

        // per-lane fold under the DMA flight
        #pragma unroll
        for (int rf = 0; rf < 4; ++rf) {
            float lmraw = acc[0][rf][0];
            #pragma unroll
            for (int cf = 0; cf < 4; ++cf)
                #pragma unroll
                for (int r = 0; r < 4; ++r)
                    if (cf | r) lmraw = fmaxf(lmraw, acc[cf][rf][r]);
            float lm = fmaxf(rm[rf], K2 * lmraw);
            float ls0 = rs[rf] * fexp2(rm[rf] - lm);
            float ls1 = 0.f;
            #pragma unroll
            for (int cf = 0; cf < 4; ++cf)
                #pragma unroll
                for (int r = 0; r < 4; ++r) {
                    float e = fexp2(fmaf(K2, acc[cf][rf][r], -lm));
                    if (cf & 1) ls1 += e; else ls0 += e;
                }
            rm[rf] = lm; rs[rf] = ls0 + ls1;
        }
    }

    // cross-lane-group merge (copies at lanes l15+16k)
    #pragma unroll
    for (int rf = 0; rf < 4; ++rf) {
        float m = rm[rf], s = rs[rf];
        float m1 = __shfl_xor(m, 16), s1 = __shfl_xor(s, 16);
        float M = fmaxf(m, m1);
        s = s * fexp2(m - M) + s1 * fexp2(m1 - M);
        m = M;
        m1 = __shfl_xor(m, 32); s1 = __shfl_xor(s, 32);
        M = fmaxf(m, m1);
        s = s * fexp2(m - M) + s1 * fexp2(m1 - M);
        if (lg == 0) {
            size_t idx = (size_t)bx * N + row0 + rf * 16 + l15;
            pm[idx] = M;
            ps[idx] = s;
        }
    }
}

// K3: per-row combine of CB partials -> lse (log2 domain); exact label logit; loss.
__global__ void finalize_kernel(const float* __restrict__ pm, const float* __restrict__ ps,
                                const float* __restrict__ xf, const float* __restrict__ lut,
                                const int* __restrict__ label, float* __restrict__ out_loss,
                                int CB, int N, int P) {
    int row = blockIdx.x, tid = threadIdx.x;
    int y = label[row];
    if (y >= P) return;   // unlabeled -> ce contribution 0
    __shared__ float sm[256], ss[256], sd[256];
    __shared__ int snz[256];
    float m = -1e30f, s = 0.f;
    for (int cb = tid; cb < CB; cb += 256) {
        float bm = pm[(size_t)cb * N + row];
        float bs = ps[(size_t)cb * N + row];
        float M = fmaxf(m, bm);
        s = s * fexp2(m - M) + bs * fexp2(bm - M);
        m = M;
    }
    float lv = lut[(size_t)y * DD + tid];
    sm[tid] = m; ss[tid] = s;
    sd[tid] = xf[(size_t)row * DD + tid] * lv;
    snz[tid] = (lv != 0.f) ? 1 : 0;
    __syncthreads();
    for (int h = 128; h > 0; h >>= 1) {
        if (tid < h) {
            float m2 = sm[tid + h], s2 = ss[tid + h];
            float M = fmaxf(sm[tid], m2);
            ss[tid] = ss[tid] * fexp2(sm[tid] - M) + s2 * fexp2(m2 - M);
            sm[tid] = M;
            sd[tid] += sd[tid + h];
            snz[tid] |= snz[tid + h];
        }
        __syncthreads();
    }
    if (tid == 0) {
        bool bad = (snz[0] == 0);          // own prototype empty -> logit forced to +30
        float lse = LN2 * (sm[0] + log2f(ss[0]));
        float llab = bad ? SCALAR : SCALAR * sd[0];
        atomicAdd(out_loss, (lse - llab) / (float)N);
    }
}

// K4: memory-bank update. One wave per sample; wave-parallel ballot scans.
__global__ __launch_bounds__(64) void update_kernel(
    const float* __restrict__ xf, const int* __restrict__ label,
    const float* __restrict__ ious, const float* __restrict__ lut,
    const int* __restrict__ header, float* __restrict__ out_lut,
    float* __restrict__ out_cq, int N, int P, int Q) {
    extern __shared__ char smem[];
    int* slab = (int*)smem;
    float* siou = (float*)(smem + sizeof(int) * (size_t)N);
    int i = blockIdx.x, lane = threadIdx.x;
    for (int j = lane; j < N; j += 64) { slab[j] = label[j]; siou[j] = ious[j]; }
    __syncthreads();

    float s = 0.f;
    for (int j = lane; j < N; j += 64) s += siou[j];
    #pragma unroll
    for (int off = 32; off > 0; off >>= 1) s += __shfl_xor(s, off);
    if (s >= 0.2f * (float)N) return;   // ious.mean() >= 0.2 -> no update

    int y = slab[i];
    if (y < P) {
        unsigned long long m[16];
        #pragma unroll
        for (int c = 0; c < 16; ++c) {
            int j = c * 64 + lane;
            m[c] = __ballot(j < N && slab[j] == y);
        }
        int first = -1;
        #pragma unroll
        for (int c = 0; c < 16; ++c)
            if (first < 0 && m[c] != 0ull) first = c * 64 + (int)__builtin_ctzll(m[c]);
        if (first != i) return;   // only the first occurrence drives this label

        float4 r = *(const float4*)(lut + (size_t)y * DD + lane * 4);
        for (int pass = 0; pass < 2; ++pass) {
            #pragma unroll
            for (int c = 0; c < 16; ++c) {
                unsigned long long mm = m[c];
                while (mm) {
                    int j = c * 64 + (int)__builtin_ctzll(mm);
                    mm &= mm - 1;
                    float b = (pass == 0) ? 0.5f : siou[j];
                    float a = 1.f - b;
                    float4 xj = *(const float4*)(xf + (size_t)j * DD + lane * 4);
                    r.x = a * r.x + b * xj.x;
                    r.y = a * r.y + b * xj.y;
                    r.z = a * r.z + b * xj.z;
                    r.w = a * r.w + b * xj.w;
                    float ss2 = r.x * r.x + r.y * r.y + r.z * r.z + r.w * r.w;
                    #pragma unroll
                    for (int off = 32; off > 0; off >>= 1) ss2 += __shfl_xor(ss2, off);
                    float inv = 1.f / fmaxf(sqrtf(ss2), 1e-12f);
                    r.x *= inv; r.y *= inv; r.z *= inv; r.w *= inv;
                }
            }
        }
        float* dst = out_lut + (size_t)y * DD + lane * 4;
        dst[0] = r.x; dst[1] = r.y; dst[2] = r.z; dst[3] = r.w;
    } else {
        int rank = 0, U = 0;
        #pragma unroll
        for (int c = 0; c < 16; ++c) {
            int j = c * 64 + lane;
            unsigned long long u = __ballot(j < N && slab[j] >= P);
            U += __popcll(u);
            int base = c * 64;
            if (base + 64 <= i)      rank += __popcll(u);
            else if (base < i)       rank += __popcll(u & ((1ull << (i - base)) - 1ull));
        }
        int h0 = header[0];
        float4 xi = *(const float4*)(xf + (size_t)i * DD + lane * 4);
        long long p1 = ((long long)h0 + rank) % Q;
        long long p2 = ((long long)h0 + U + rank) % Q;
        float* d1 = out_cq + (size_t)p1 * DD + lane * 4;
        float* d2 = out_cq + (size_t)p2 * DD + lane * 4;
        d1[0] = xi.x; d1[1] = xi.y; d1[2] = xi.z; d1[3] = xi.w;
        d2[0] = xi.x; d2[1] = xi.y; d2[2] = xi.z; d2[3] = xi.w;
    }
}

extern "C" void kernel_launch(void* const* d_in, const int* in_sizes, int n_in,
                              void* d_out, int out_size, void* d_ws, size_t ws_size,
                              hipStream_t stream) {
    const float* inputs = (const float*)d_in[0];
    const int* label    = (const int*)d_in[1];
    const float* ious   = (const float*)d_in[2];
    const float* lut    = (const float*)d_in[3];
    const float* cq     = (const float*)d_in[4];
    const int* header   = (const int*)d_in[5];
    float* out = (float*)d_out;

    int N = in_sizes[0] / DD;            // 1024
    int P = in_sizes[3] / DD;            // 100000
    int Q = in_sizes[4] / DD;            // 50000
    int C = P + Q;                       // 150000
    int TILES = (C + 63) / 64;           // 2344
    int GB = (TILES + NT - 1) / NT;      // 293 column-groups (2344 = 293*8 exact)
    long PD = (long)P * DD;
    long TOT = (long)C * DD;

    // workspace: xf(1MB) | xb(0.5MB) | pm(1.2MB) | ps(1.2MB) | bt(76.9MB)
    char* ws = (char*)d_ws;
    float* xf = (float*)ws;
    unsigned short* xb = (unsigned short*)(ws + (size_t)N * DD * 4);
    float* pm = (float*)(ws + (size_t)N * DD * 6);
    float* ps = pm + (size_t)GB * N;
    unsigned short* bt = (unsigned short*)((char*)(ps + (size_t)GB * N));

    float* out_loss = out;
    float* out_lut  = out + 1;
    float* out_cq   = out + 1 + (size_t)P * DD;

    hipLaunchKernelGGL(prep_bt_copy_kernel, dim3(N + TILES), dim3(256), 0, stream,
                       inputs, xf, xb, lut, cq, out, bt, PD, TOT, C, TILES, N);
    hipLaunchKernelGGL(gemm_lse_kernel, dim3(GB, N / 256), dim3(256), 0, stream,
                       xb, bt, pm, ps, N);
    hipLaunchKernelGGL(finalize_kernel, dim3(N), dim3(256), 0, stream,
                       pm, ps, xf, lut, label, out_loss, GB, N, P);
    hipLaunchKernelGGL(update_kernel, dim3(N), dim3(64), (size_t)N * 8, stream,
                       xf, label, ious, lut, header, out_lut, out_cq, N, P, Q);
}

// Round 18
// 184.383 us; speedup vs baseline: 1.2720x; 1.0705x over previous
//
#include <hip/hip_runtime.h>
#include <hip/hip_bf16.h>

#define DD 256
#define SCALAR 30.0f
#define K2 43.28085122666891f     // 30 * log2(e)
#define LN2 0.6931471805599453f
#define NT 16                     // 32-col half-tiles (16KB) per gemm block; 4688 = 293*16

typedef __attribute__((ext_vector_type(8))) short bf16x8;
typedef __attribute__((ext_vector_type(4))) float f32x4;

__device__ __forceinline__ float fexp2(float x) {
#if __has_builtin(__builtin_amdgcn_exp2f)
    return __builtin_amdgcn_exp2f(x);
#else
    return exp2f(x);
#endif
}

// RNE float->bf16 (no-NaN inputs)
__device__ __forceinline__ unsigned short f2b(float f) {
    unsigned int u = __builtin_bit_cast(unsigned int, f);
    u += 0x7FFFu + ((u >> 16) & 1u);
    return (unsigned short)(u >> 16);
}

// async global->LDS, 16B per lane; LDS dest is wave-uniform base + lane*16
__device__ __forceinline__ void gload16(const void* g, void* l) {
    __builtin_amdgcn_global_load_lds((const __attribute__((address_space(1))) void*)g,
                                     (__attribute__((address_space(3))) void*)l, 16, 0, 0);
}

// K1 (R13 structure; ONE change: plain stores instead of nontemporal).
// blocks [0,N): prep (x=l2norm, xf/xb, zero loss).
// blocks [N, N+2048): bt tile-image build + aligned out-copy.
// bt: global col C occupies 512B at byte C*512; bf16(C,k) at
//   C*512 + ((k>>3)^(C&7))*16 + (k&7)*2  (pre-baked inverse of gemm ds_read swizzle).
__global__ __launch_bounds__(256) void prep_convert_copy_kernel(
    const float* __restrict__ in, float* __restrict__ xf, unsigned short* __restrict__ xb,
    const float* __restrict__ lut, const float* __restrict__ cq,
    float* __restrict__ out, unsigned short* __restrict__ bt,
    long PD, long TOT, int C, int CT, int N) {
    __shared__ float red[256];
    int tid = threadIdx.x;
    if ((int)blockIdx.x < N) {
        int row = blockIdx.x;
        float v = in[(size_t)row * DD + tid];
        red[tid] = v * v;
        __syncthreads();
        for (int h = 128; h > 0; h >>= 1) {
            if (tid < h) red[tid] += red[tid + h];
            __syncthreads();
        }
        float nrm = fmaxf(sqrtf(red[0]), 1e-12f);
        float xn = v / nrm;
        xf[(size_t)row * DD + tid] = xn;
        xb[(size_t)row * DD + tid] = f2b(xn);
        if (row == 0 && tid == 0) out[0] = 0.f;
        return;
    }
    int lane = tid & 63;
    int wid = ((blockIdx.x - N) * blockDim.x + tid) >> 6;
    int nw = (2048 * 256) >> 6;
    for (int gc = wid; gc < CT; gc += nw) {
        int t = gc >> 6, c = gc & 63;
        char* tbase = (char*)bt + (size_t)t * 32768;
        long toff = (long)c * 512 + (long)((((lane >> 1) ^ (c & 7)) << 4) + (lane & 1) * 8);
        if (gc >= C) {   // phantom columns -> zero (logit 0, negligible in lse)
            *(short4*)(tbase + toff) = make_short4(0, 0, 0, 0);
            continue;
        }
        long base = (long)gc * 256;
        long s = base + lane * 4;
        float4 v = (s < PD) ? *(const float4*)(lut + s) : *(const float4*)(cq + (s - PD));
        short4 b;
        b.x = f2b(v.x); b.y = f2b(v.y); b.z = f2b(v.z); b.w = f2b(v.w);
        *(short4*)(tbase + toff) = b;
        // aligned out-copy: out[base+4l .. +3] = flat[base+4l-1 .. +2]
        float pw = __shfl_up(v.w, 1);
        if (lane == 0 && base > 0) {
            long sp = base - 1;
            pw = (sp < PD) ? lut[sp] : cq[sp - PD];
        }
        if (gc == 0 && lane == 0) {
            out[1] = v.x; out[2] = v.y; out[3] = v.z;   // out[0] is the loss
        } else {
            f32x4 o = (f32x4){pw, v.x, v.y, v.z};
            *(f32x4*)(out + base + lane * 4) = o;       // PLAIN store (was nt): A/B the 3TB/s cap
        }
        if (gc == C - 1 && lane == 63) out[TOT] = v.w;
    }
}

// K2: GEMM + per-row (max,sumexp), log2 domain — OCCUPANCY restructure:
// 32 rows/wave (areg 64 VGPR, acc 16 AGPR, total ~110 <= 128 -> 4 waves/SIMD),
// 32-col half-tiles (16KB; dbuf 32KB -> 4 blocks/CU within 160KB LDS).
// grid (293 bx, 8 rb); bt half-tiles are contiguous 16KB (bt is globally
// col-major by 512B). 8 rb-readers of bt are L3-served (R13: FETCH=79=1 pass).
// Counted vmcnt: 4 loads/tile/wave -> vmcnt(4); fold under the DMA flight.
__global__ __launch_bounds__(256, 4) void gemm_lse_kernel(
    const unsigned short* __restrict__ xb, const unsigned short* __restrict__ bt,
    float* __restrict__ pm, float* __restrict__ ps, int N) {
    __shared__ char Bs[2][16384];
    int tid = threadIdx.x;
    int w = tid >> 6, lane = tid & 63;
    int l15 = lane & 15, lg = lane >> 4;
    int bx = blockIdx.x, rb = blockIdx.y;
    int row0 = rb * 128 + w * 32;
    int xr = l15 & 7;

    const char* gt = (const char*)bt + (size_t)bx * (NT * 16384);

    // A -> registers FIRST (oldest in vmcnt order): 2 rf x 8 kc x 16B = 64 VGPR
    bf16x8 areg[2][8];
    const char* ab = (const char*)xb + ((size_t)(row0 + l15) * 256 + lg * 8) * 2;
    #pragma unroll
    for (int rf = 0; rf < 2; ++rf)
        #pragma unroll
        for (int kc = 0; kc < 8; ++kc)
            areg[rf][kc] = *(const bf16x8*)(ab + rf * (16 * 512) + kc * 64);

    // then DMA tiles 0 and 1 (newest 8 vmem ops; 4KB per wave per tile)
    {
        const char* src = gt + w * 4096 + lane * 16;
        #pragma unroll
        for (int i = 0; i < 4; ++i)
            gload16(src + i * 1024, &Bs[0][w * 4096 + i * 1024]);
        #pragma unroll
        for (int i = 0; i < 4; ++i)
            gload16(src + 16384 + i * 1024, &Bs[1][w * 4096 + i * 1024]);
    }

    float rm[2], rs[2];
    #pragma unroll
    for (int rf = 0; rf < 2; ++rf) { rm[rf] = -1e30f; rs[rf] = 0.f; }

    #pragma unroll 1
    for (int st = 0; st < NT; ++st) {
        if (st < NT - 1) asm volatile("s_waitcnt vmcnt(4)" ::: "memory");
        else             asm volatile("s_waitcnt vmcnt(0)" ::: "memory");
        __builtin_amdgcn_s_barrier();

        const char* bufc = &Bs[st & 1][0];
        f32x4 acc[2][2];   // [cf][rf] -> 16 AGPR
        #pragma unroll
        for (int cf = 0; cf < 2; ++cf)
            #pragma unroll
            for (int rf = 0; rf < 2; ++rf) acc[cf][rf] = (f32x4){0.f, 0.f, 0.f, 0.f};

        #pragma unroll
        for (int k0 = 0; k0 < 8; ++k0) {
            int sl = (((k0 * 4 + lg) ^ xr) << 4);
            bf16x8 b[2];
            #pragma unroll
            for (int cf = 0; cf < 2; ++cf)
                b[cf] = *(const bf16x8*)(bufc + (cf * 16 + l15) * 512 + sl);
            #pragma unroll
            for (int rf = 0; rf < 2; ++rf)
                #pragma unroll
                for (int cf = 0; cf < 2; ++cf)
                    acc[cf][rf] = __builtin_amdgcn_mfma_f32_16x16x32_bf16(b[cf], areg[rf][k0], acc[cf][rf], 0, 0, 0);
        }

        __builtin_amdgcn_s_barrier();
        if (st + 2 < NT) {
            const char* src = gt + (st + 2) * 16384 + w * 4096 + lane * 16;
            char* dst = &Bs[st & 1][w * 4096];
            #pragma unroll
            for (int i = 0; i < 4; ++i)
                gload16(src + i * 1024, dst + i * 1024);
        }

        // per-lane fold under the DMA flight
        #pragma unroll
        for (int rf = 0; rf < 2; ++rf) {
            float lmraw = acc[0][rf][0];
            #pragma unroll
            for (int cf = 0; cf < 2; ++cf)
                #pragma unroll
                for (int r = 0; r < 4; ++r)
                    if (cf | r) lmraw = fmaxf(lmraw, acc[cf][rf][r]);
            float lm = fmaxf(rm[rf], K2 * lmraw);
            float ls0 = rs[rf] * fexp2(rm[rf] - lm);
            float ls1 = 0.f;
            #pragma unroll
            for (int cf = 0; cf < 2; ++cf)
                #pragma unroll
                for (int r = 0; r < 4; ++r) {
                    float e = fexp2(fmaf(K2, acc[cf][rf][r], -lm));
                    if (cf & 1) ls1 += e; else ls0 += e;
                }
            rm[rf] = lm; rs[rf] = ls0 + ls1;
        }
    }

    // cross-lane-group merge (copies at lanes l15+16k)
    #pragma unroll
    for (int rf = 0; rf < 2; ++rf) {
        float m = rm[rf], s = rs[rf];
        float m1 = __shfl_xor(m, 16), s1 = __shfl_xor(s, 16);
        float M = fmaxf(m, m1);
        s = s * fexp2(m - M) + s1 * fexp2(m1 - M);
        m = M;
        m1 = __shfl_xor(m, 32); s1 = __shfl_xor(s, 32);
        M = fmaxf(m, m1);
        s = s * fexp2(m - M) + s1 * fexp2(m1 - M);
        if (lg == 0) {
            size_t idx = (size_t)bx * N + row0 + rf * 16 + l15;
            pm[idx] = M;
            ps[idx] = s;
        }
    }
}

// K3: per-row combine of CB partials -> lse (log2 domain); exact label logit; loss.
__global__ void finalize_kernel(const float* __restrict__ pm, const float* __restrict__ ps,
                                const float* __restrict__ xf, const float* __restrict__ lut,
                                const int* __restrict__ label, float* __restrict__ out_loss,
                                int CB, int N, int P) {
    int row = blockIdx.x, tid = threadIdx.x;
    int y = label[row];
    if (y >= P) return;   // unlabeled -> ce contribution 0
    __shared__ float sm[256], ss[256], sd[256];
    __shared__ int snz[256];
    float m = -1e30f, s = 0.f;
    for (int cb = tid; cb < CB; cb += 256) {
        float bm = pm[(size_t)cb * N + row];
        float bs = ps[(size_t)cb * N + row];
        float M = fmaxf(m, bm);
        s = s * fexp2(m - M) + bs * fexp2(bm - M);
        m = M;
    }
    float lv = lut[(size_t)y * DD + tid];
    sm[tid] = m; ss[tid] = s;
    sd[tid] = xf[(size_t)row * DD + tid] * lv;
    snz[tid] = (lv != 0.f) ? 1 : 0;
    __syncthreads();
    for (int h = 128; h > 0; h >>= 1) {
        if (tid < h) {
            float m2 = sm[tid + h], s2 = ss[tid + h];
            float M = fmaxf(sm[tid], m2);
            ss[tid] = ss[tid] * fexp2(sm[tid] - M) + s2 * fexp2(m2 - M);
            sm[tid] = M;
            sd[tid] += sd[tid + h];
            snz[tid] |= snz[tid + h];
        }
        __syncthreads();
    }
    if (tid == 0) {
        bool bad = (snz[0] == 0);          // own prototype empty -> logit forced to +30
        float lse = LN2 * (sm[0] + log2f(ss[0]));
        float llab = bad ? SCALAR : SCALAR * sd[0];
        atomicAdd(out_loss, (lse - llab) / (float)N);
    }
}

// K4: memory-bank update. One wave per sample; wave-parallel ballot scans.
__global__ __launch_bounds__(64) void update_kernel(
    const float* __restrict__ xf, const int* __restrict__ label,
    const float* __restrict__ ious, const float* __restrict__ lut,
    const int* __restrict__ header, float* __restrict__ out_lut,
    float* __restrict__ out_cq, int N, int P, int Q) {
    extern __shared__ char smem[];
    int* slab = (int*)smem;
    float* siou = (float*)(smem + sizeof(int) * (size_t)N);
    int i = blockIdx.x, lane = threadIdx.x;
    for (int j = lane; j < N; j += 64) { slab[j] = label[j]; siou[j] = ious[j]; }
    __syncthreads();

    float s = 0.f;
    for (int j = lane; j < N; j += 64) s += siou[j];
    #pragma unroll
    for (int off = 32; off > 0; off >>= 1) s += __shfl_xor(s, off);
    if (s >= 0.2f * (float)N) return;   // ious.mean() >= 0.2 -> no update

    int y = slab[i];
    if (y < P) {
        unsigned long long m[16];
        #pragma unroll
        for (int c = 0; c < 16; ++c) {
            int j = c * 64 + lane;
            m[c] = __ballot(j < N && slab[j] == y);
        }
        int first = -1;
        #pragma unroll
        for (int c = 0; c < 16; ++c)
            if (first < 0 && m[c] != 0ull) first = c * 64 + (int)__builtin_ctzll(m[c]);
        if (first != i) return;   // only the first occurrence drives this label

        float4 r = *(const float4*)(lut + (size_t)y * DD + lane * 4);
        for (int pass = 0; pass < 2; ++pass) {
            #pragma unroll
            for (int c = 0; c < 16; ++c) {
                unsigned long long mm = m[c];
                while (mm) {
                    int j = c * 64 + (int)__builtin_ctzll(mm);
                    mm &= mm - 1;
                    float b = (pass == 0) ? 0.5f : siou[j];
                    float a = 1.f - b;
                    float4 xj = *(const float4*)(xf + (size_t)j * DD + lane * 4);
                    r.x = a * r.x + b * xj.x;
                    r.y = a * r.y + b * xj.y;
                    r.z = a * r.z + b * xj.z;
                    r.w = a * r.w + b * xj.w;
                    float ss2 = r.x * r.x + r.y * r.y + r.z * r.z + r.w * r.w;
                    #pragma unroll
                    for (int off = 32; off > 0; off >>= 1) ss2 += __shfl_xor(ss2, off);
                    float inv = 1.f / fmaxf(sqrtf(ss2), 1e-12f);
                    r.x *= inv; r.y *= inv; r.z *= inv; r.w *= inv;
                }
            }
        }
        float* dst = out_lut + (size_t)y * DD + lane * 4;
        dst[0] = r.x; dst[1] = r.y; dst[2] = r.z; dst[3] = r.w;
    } else {
        int rank = 0, U = 0;
        #pragma unroll
        for (int c = 0; c < 16; ++c) {
            int j = c * 64 + lane;
            unsigned long long u = __ballot(j < N && slab[j] >= P);
            U += __popcll(u);
            int base = c * 64;
            if (base + 64 <= i)      rank += __popcll(u);
            else if (base < i)       rank += __popcll(u & ((1ull << (i - base)) - 1ull));
        }
        int h0 = header[0];
        float4 xi = *(const float4*)(xf + (size_t)i * DD + lane * 4);
        long long p1 = ((long long)h0 + rank) % Q;
        long long p2 = ((long long)h0 + U + rank) % Q;
        float* d1 = out_cq + (size_t)p1 * DD + lane * 4;
        float* d2 = out_cq + (size_t)p2 * DD + lane * 4;
        d1[0] = xi.x; d1[1] = xi.y; d1[2] = xi.z; d1[3] = xi.w;
        d2[0] = xi.x; d2[1] = xi.y; d2[2] = xi.z; d2[3] = xi.w;
    }
}

extern "C" void kernel_launch(void* const* d_in, const int* in_sizes, int n_in,
                              void* d_out, int out_size, void* d_ws, size_t ws_size,
                              hipStream_t stream) {
    const float* inputs = (const float*)d_in[0];
    const int* label    = (const int*)d_in[1];
    const float* ious   = (const float*)d_in[2];
    const float* lut    = (const float*)d_in[3];
    const float* cq     = (const float*)d_in[4];
    const int* header   = (const int*)d_in[5];
    float* out = (float*)d_out;

    int N = in_sizes[0] / DD;            // 1024
    int P = in_sizes[3] / DD;            // 100000
    int Q = in_sizes[4] / DD;            // 50000
    int C = P + Q;                       // 150000
    int TILES = (C + 63) / 64;           // 2344 (64-col bt build tiles)
    int SUB = TILES * 2;                 // 4688 32-col half-tiles
    int GB = SUB / NT;                   // 293 gemm column-groups
    int CT = TILES * 64;                 // 150016 padded columns
    long PD = (long)P * DD;
    long TOT = (long)C * DD;

    // workspace: xf(1MB) | xb(0.5MB) | pm(1.2MB) | ps(1.2MB) | bt(76.9MB)
    char* ws = (char*)d_ws;
    float* xf = (float*)ws;
    unsigned short* xb = (unsigned short*)(ws + (size_t)N * DD * 4);
    float* pm = (float*)(ws + (size_t)N * DD * 6);
    float* ps = pm + (size_t)GB * N;
    unsigned short* bt = (unsigned short*)((char*)(ps + (size_t)GB * N));

    float* out_loss = out;
    float* out_lut  = out + 1;
    float* out_cq   = out + 1 + (size_t)P * DD;

    hipLaunchKernelGGL(prep_convert_copy_kernel, dim3(N + 2048), dim3(256), 0, stream,
                       inputs, xf, xb, lut, cq, out, bt, PD, TOT, C, CT, N);
    hipLaunchKernelGGL(gemm_lse_kernel, dim3(GB, N / 128), dim3(256), 0, stream,
                       xb, bt, pm, ps, N);
    hipLaunchKernelGGL(finalize_kernel, dim3(N), dim3(256), 0, stream,
                       pm, ps, xf, lut, label, out_loss, GB, N, P);
    hipLaunchKernelGGL(update_kernel, dim3(N), dim3(64), (size_t)N * 8, stream,
                       xf, label, ious, lut, header, out_lut, out_cq, N, P, Q);
}